// Round 6
// baseline (162.392 us; speedup 1.0000x reference)
//
#include <hip/hip_runtime.h>
#include <hip/hip_bf16.h>
#include <math.h>

#define DIM 512
#define NHEAD 8
#define HD 64
#define NBANK 4096
#define NQROWS 4096
#define EPS 1e-5f
// 0.125 * log2(e): exp() folded into exp2() domain at the Q epilogue
#define QSCALE 0.18033688011f
#define PART_ELEMS (NQROWS * DIM)   // one O-partial buffer (bf16 elems)

typedef __attribute__((ext_vector_type(4))) float floatx4;
typedef __attribute__((ext_vector_type(8))) short short8;

#if defined(__has_builtin)
#if __has_builtin(__builtin_amdgcn_exp2f)
#define EXP2(x) __builtin_amdgcn_exp2f(x)
#endif
#endif
#ifndef EXP2
#define EXP2(x) exp2f(x)
#endif

__device__ __forceinline__ unsigned short f2bf(float f) {
    unsigned int u = __float_as_uint(f);
    u += 0x7fffu + ((u >> 16) & 1u);          // round-to-nearest-even
    return (unsigned short)(u >> 16);
}
__device__ __forceinline__ float bf2f(unsigned short h) {
    return __uint_as_float(((unsigned int)h) << 16);
}
// packed fp32x2 -> bf16x2 (v_cvt_pk_bf16_f32), low short = a
__device__ __forceinline__ unsigned int pk2(float a, float b) {
    union { __hip_bfloat162 h; unsigned int u; } cvt;
    cvt.h = __float22bfloat162_rn(make_float2(a, b));
    return cvt.u;
}
// async 16B global -> LDS DMA (global_load_lds_dwordx4).  gsrc per-lane,
// ldst wave-uniform slab base; HW adds lane*16.
__device__ __forceinline__ void dma16(const void* gsrc, void* ldst) {
    __builtin_amdgcn_global_load_lds(
        (const __attribute__((address_space(1))) unsigned int*)gsrc,
        (__attribute__((address_space(3))) unsigned int*)ldst, 16, 0, 0);
}

// ---------------------------------------------------------------------------
// cvt_kernel: fp32 -> bf16, SEG-SWIZZLED per 64-elem k-tile:
// dst[row][kt][seg^(row&7)] = src[row][kt*64+seg*8 ..8] -> consumers DMA linearly.
// blockIdx.y 0..3 = Wq/Wk/Wv/Wp (512x512, 128 blocks); 4..6 = xq/xk/xv
// (4096x512, 1024 blocks).
// ---------------------------------------------------------------------------
__global__ __launch_bounds__(256) void cvt_kernel(
    const float* __restrict__ Wq, const float* __restrict__ Wk,
    const float* __restrict__ Wv, const float* __restrict__ Wp,
    const float* __restrict__ xq, const float* __restrict__ xk,
    const float* __restrict__ xv,
    unsigned short* __restrict__ Wb, unsigned short* __restrict__ Xb)
{
    const int y = blockIdx.y;
    const float* src;
    unsigned short* dst;
    if (y < 4) {
        if (blockIdx.x >= 128) return;        // W mats are 16x smaller
        src = (y == 0) ? Wq : (y == 1) ? Wk : (y == 2) ? Wv : Wp;
        dst = Wb + (size_t)y * DIM * DIM;
    } else {
        src = (y == 4) ? xq : (y == 5) ? xk : xv;
        dst = Xb + (size_t)(y - 4) * NQROWS * DIM;
    }
    const int i = (blockIdx.x * 256 + threadIdx.x) * 8;
    const int row = i >> 9, kpos = i & 511;
    const int kt = kpos >> 6, seg = (kpos >> 3) & 7;
    const float4 a0 = *(const float4*)(src + i);
    const float4 a1 = *(const float4*)(src + i + 4);
    union { short8 v; unsigned int u[4]; } t;
    t.u[0] = pk2(a0.x, a0.y); t.u[1] = pk2(a0.z, a0.w);
    t.u[2] = pk2(a1.x, a1.y); t.u[3] = pk2(a1.z, a1.w);
    *(short8*)(dst + (size_t)row * 512 + kt * 64 + ((seg ^ (row & 7)) << 3)) = t.v;
}

// ---------------------------------------------------------------------------
// qkv_kernel: 64x128 tiles, ping-pong, one barrier/k-iter.  BOTH operands
// (pre-swizzled bf16 Xb / Wb) staged via global_load_lds DMA.
// Epilogues write ATTN-READY layouts.
// ---------------------------------------------------------------------------
__global__ __launch_bounds__(256) void qkv_kernel(
    const unsigned short* __restrict__ Xb, const unsigned short* __restrict__ Wb,
    const float* __restrict__ qg, const float* __restrict__ qbeta,
    const float* __restrict__ kg, const float* __restrict__ kbeta,
    unsigned short* __restrict__ Qb, unsigned short* __restrict__ Kb,
    unsigned short* __restrict__ VTb)
{
    __shared__ short8 smem[3072];   // 48 KB: buf p = smem + p*1536 (A 512 | B 1024)
    const int tid  = threadIdx.x;
    const int w    = tid >> 6, lane = tid & 63, m = lane & 15, q = lane >> 4;
    const int wr   = w & 1, wc = w >> 1;
    const int row0 = blockIdx.x * 64;
    const int mat  = blockIdx.y >> 2;
    const int col0 = (blockIdx.y & 3) * 128;
    const unsigned short* Xm = Xb + (size_t)mat * NQROWS * DIM;
    const unsigned short* Wm = Wb + (size_t)mat * DIM * DIM;

    // DMA sources: per-lane global addr, wave-uniform LDS dest slab.
    const int it0 = tid, it1 = tid + 256;
    const unsigned short* asrc0 = Xm + (size_t)(row0 + (it0 >> 3)) * DIM + (it0 & 7) * 8;
    const unsigned short* asrc1 = Xm + (size_t)(row0 + (it1 >> 3)) * DIM + (it1 & 7) * 8;
    const unsigned short* bsrc[4];
    #pragma unroll
    for (int j = 0; j < 4; ++j) {
        const int item = j * 256 + tid;
        bsrc[j] = Wm + (size_t)(col0 + (item >> 3)) * DIM + (item & 7) * 8;
    }

    floatx4 acc[2][4];
    #pragma unroll
    for (int mt = 0; mt < 2; ++mt)
        #pragma unroll
        for (int nt = 0; nt < 4; ++nt) acc[mt][nt] = (floatx4){0.f, 0.f, 0.f, 0.f};

    {   // DMA tile 0 -> buf0
        short8* as = smem; short8* bs = smem + 512;
        dma16(asrc0, as + w * 64);
        dma16(asrc1, as + 256 + w * 64);
        #pragma unroll
        for (int j = 0; j < 4; ++j)
            dma16(bsrc[j], bs + j * 256 + w * 64);
    }
    __syncthreads();

    for (int kt = 0; kt < 8; ++kt) {
        short8* as = smem + (kt & 1) * 1536;
        short8* bs = as + 512;
        if (kt < 7) {              // DMA tile kt+1 -> other buf (overlaps compute)
            short8* asn = smem + ((kt + 1) & 1) * 1536;
            short8* bsn = asn + 512;
            const int o = (kt + 1) * 64;
            dma16(asrc0 + o, asn + w * 64);
            dma16(asrc1 + o, asn + 256 + w * 64);
            #pragma unroll
            for (int j = 0; j < 4; ++j)
                dma16(bsrc[j] + o, bsn + j * 256 + w * 64);
        }
        #pragma unroll
        for (int s = 0; s < 2; ++s) {
            short8 af[2], bfr[4];
            #pragma unroll
            for (int mt = 0; mt < 2; ++mt)
                af[mt] = as[(wr * 32 + mt * 16 + m) * 8 + ((s * 4 + q) ^ (m & 7))];
            #pragma unroll
            for (int nt = 0; nt < 4; ++nt)
                bfr[nt] = bs[(wc * 64 + nt * 16 + m) * 8 + ((s * 4 + q) ^ (m & 7))];
            #pragma unroll
            for (int mt = 0; mt < 2; ++mt)
                #pragma unroll
                for (int nt = 0; nt < 4; ++nt)
                    acc[mt][nt] = __builtin_amdgcn_mfma_f32_16x16x32_bf16(af[mt], bfr[nt], acc[mt][nt], 0, 0, 0);
        }
        __syncthreads();
    }

    if (mat < 2) {
        const float* g = (mat == 0) ? qg : kg;
        const float* be = (mat == 0) ? qbeta : kbeta;
        unsigned short* Y = (mat == 0) ? Qb : Kb;
        float gv[4], bv[4];
        #pragma unroll
        for (int nt = 0; nt < 4; ++nt) { gv[nt] = g[nt * 16 + m]; bv[nt] = be[nt * 16 + m]; }
        #pragma unroll
        for (int mt = 0; mt < 2; ++mt) {
            #pragma unroll
            for (int r = 0; r < 4; ++r) {
                float s = 0.f, sq = 0.f;
                #pragma unroll
                for (int nt = 0; nt < 4; ++nt) { const float v = acc[mt][nt][r]; s += v; sq += v * v; }
                s  += __shfl_xor(s, 1);  s  += __shfl_xor(s, 2);  s  += __shfl_xor(s, 4);  s  += __shfl_xor(s, 8);
                sq += __shfl_xor(sq, 1); sq += __shfl_xor(sq, 2); sq += __shfl_xor(sq, 4); sq += __shfl_xor(sq, 8);
                const float mean = s * (1.f / HD);
                const float var  = sq * (1.f / HD) - mean * mean;
                const float rr   = rsqrtf(var + EPS);
                const int grow = row0 + wr * 32 + mt * 16 + q * 4 + r;
                #pragma unroll
                for (int nt = 0; nt < 4; ++nt) {
                    float v = (acc[mt][nt][r] - mean) * rr * gv[nt] + bv[nt];
                    if (mat == 0) v *= QSCALE;
                    const int col = col0 + wc * 64 + nt * 16 + m;
                    int scol = col;
                    if (mat == 1) {   // K: seg-swizzle within head slice by n
                        const int o = col & 63, sg2 = o >> 3;
                        scol = (col & ~63) | (((sg2 ^ (grow & 7)) << 3) | (o & 7));
                    }
                    Y[(size_t)grow * DIM + scol] = f2bf(v);
                }
            }
        }
    } else {
        // V: transpose via LDS (stride 88), then pack VTb[h][chunk][item]
        // item(d,g) = dl*8 + (g^(dl&7)); value = rows {pos..pos+3, pos+16..+19}
        unsigned short* vt = (unsigned short*)smem;
        __syncthreads();
        #pragma unroll
        for (int mt = 0; mt < 2; ++mt)
            #pragma unroll
            for (int nt = 0; nt < 4; ++nt) {
                const int c  = wc * 64 + nt * 16 + m;
                const int rw = wr * 32 + mt * 16 + q * 4;
                *(unsigned int*)(vt + c * 88 + rw)     = pk2(acc[mt][nt][0], acc[mt][nt][1]);
                *(unsigned int*)(vt + c * 88 + rw + 2) = pk2(acc[mt][nt][2], acc[mt][nt][3]);
            }
        __syncthreads();
        #pragma unroll
        for (int p = 0; p < 4; ++p) {
            const int idx = p * 256 + tid;       // 1024 = 128 c x 8 g
            const int c = idx >> 3, g = idx & 7;
            const int dglob = col0 + c, hh = dglob >> 6, dl = dglob & 63;
            const int pos = (g >> 2) * 32 + (g & 3) * 4;
            union { short8 v; ushort4 h4[2]; } tv;
            tv.h4[0] = *(const ushort4*)(vt + c * 88 + pos);
            tv.h4[1] = *(const ushort4*)(vt + c * 88 + pos + 16);
            *(short8*)(VTb + ((size_t)(hh * 64 + blockIdx.x) * 512
                              + dl * 8 + (g ^ (dl & 7))) * 8) = tv.v;
        }
    }
}

// ---------------------------------------------------------------------------
// attn_kernel R15: R13 structure (K triple / V double buffered, 40 KB LDS =
// 4 blocks/CU, counted vmcnt(2), unrolled) + row-sums moved OFF the saturated
// VALU issue port onto the 30%-idle matrix pipe: sacc += ones * P (4 MFMA
// per chunk replaces 32 v_add + 2 shuffles).  Issue-port relief.
// ---------------------------------------------------------------------------
__global__ __launch_bounds__(256, 4) void attn_kernel(
    const unsigned short* __restrict__ Qb, const unsigned short* __restrict__ Kb,
    const unsigned short* __restrict__ VTb, unsigned short* __restrict__ AOp,
    float* __restrict__ sums)
{
    // 40 KB: kbuf p = smem + p*512 (p=0..2), vbuf p = smem + 1536 + p*512 (p=0..1)
    __shared__ short8 smem[2560];
    const int tid  = threadIdx.x;
    const int w    = tid >> 6;
    const int lane = tid & 63;
    const int m    = lane & 15;
    const int Qd   = lane >> 4;
    const int h    = blockIdx.x & 7;
    const int qgi  = blockIdx.x >> 3;        // 0..31
    const int row0 = qgi * 128;
    const int part = blockIdx.y;
    const int c0   = part * 16;              // first chunk index

    // per-lane DMA sources (chunk-relative), 2 items each for K and V
    const int it0 = tid, it1 = tid + 256;    // item indices
    const unsigned short* ksrc0 = Kb + (size_t)(it0 >> 3) * DIM + h * HD + (it0 & 7) * 8;
    const unsigned short* ksrc1 = Kb + (size_t)(it1 >> 3) * DIM + h * HD + (it1 & 7) * 8;
    const unsigned short* vbase = VTb + (size_t)h * 64 * 512 * 8;

    short8 qf[2][2];
    #pragma unroll
    for (int mt = 0; mt < 2; ++mt)
        #pragma unroll
        for (int s = 0; s < 2; ++s)
            qf[mt][s] = *(const short8*)(Qb + (size_t)(row0 + w * 32 + mt * 16 + m) * DIM
                                         + h * HD + s * 32 + Qd * 8);

    floatx4 of[4][2];
    floatx4 sacc[2];
    #pragma unroll
    for (int t = 0; t < 4; ++t)
        #pragma unroll
        for (int mt = 0; mt < 2; ++mt) of[t][mt] = (floatx4){0.f, 0.f, 0.f, 0.f};
    #pragma unroll
    for (int mt = 0; mt < 2; ++mt) sacc[mt] = (floatx4){0.f, 0.f, 0.f, 0.f};
    const floatx4 fz = (floatx4){0.f, 0.f, 0.f, 0.f};
    union { short8 v; unsigned int u[4]; } onesu;
    #pragma unroll
    for (int u = 0; u < 4; ++u) onesu.u[u] = 0x3F803F80u;   // bf16 1.0 x2

    // prologue (issue order matters for vmcnt counts): K[0], V[0], K[1]
    {
        dma16(ksrc0 + (size_t)c0 * 64 * DIM, smem + w * 64);
        dma16(ksrc1 + (size_t)c0 * 64 * DIM, smem + 256 + w * 64);
        dma16(vbase + ((size_t)c0 * 512 + it0) * 8, smem + 1536 + w * 64);
        dma16(vbase + ((size_t)c0 * 512 + it1) * 8, smem + 1536 + 256 + w * 64);
        dma16(ksrc0 + ((size_t)c0 + 1) * 64 * DIM, smem + 512 + w * 64);
        dma16(ksrc1 + ((size_t)c0 + 1) * 64 * DIM, smem + 512 + 256 + w * 64);
    }

    #pragma unroll
    for (int c = 0; c < 16; ++c) {
        // queue (oldest->newest): K[c](2), V[c](2), K[c+1](2).
        // Need K[c],V[c] -> leave K[c+1]'s 2 in flight.
        if (c < 15) asm volatile("s_waitcnt vmcnt(2)" ::: "memory");
        else        asm volatile("s_waitcnt vmcnt(0)" ::: "memory");
        __builtin_amdgcn_s_barrier();
        __builtin_amdgcn_sched_barrier(0);

        short8* ks  = smem + (c % 3) * 512;
        short8* vts = smem + 1536 + (c & 1) * 512;
        if (c < 15) {            // V[c+1] -> buffer of V[c-1] (read done at barrier)
            short8* vtsn = smem + 1536 + ((c + 1) & 1) * 512;
            const size_t nc = (size_t)(c0 + c + 1);
            dma16(vbase + (nc * 512 + it0) * 8, vtsn + w * 64);
            dma16(vbase + (nc * 512 + it1) * 8, vtsn + 256 + w * 64);
        }
        if (c < 14) {            // K[c+2] -> buffer of K[c-1] (read done at barrier)
            short8* ksn = smem + ((c + 2) % 3) * 512;
            const size_t nc2 = (size_t)(c0 + c + 2);
            dma16(ksrc0 + nc2 * 64 * DIM, ksn + w * 64);
            dma16(ksrc1 + nc2 * 64 * DIM, ksn + 256 + w * 64);
        }

        // ---- S^T = K Q^T (zero-C first MFMA: no st zero-init movs) ----
        floatx4 st[4][2];
        #pragma unroll
        for (int t = 0; t < 4; ++t) {
            const short8 kf = ks[(t * 16 + m) * 8 + (Qd ^ (m & 7))];
            #pragma unroll
            for (int mt = 0; mt < 2; ++mt)
                st[t][mt] = __builtin_amdgcn_mfma_f32_16x16x32_bf16(kf, qf[mt][0], fz, 0, 0, 0);
        }
        #pragma unroll
        for (int t = 0; t < 4; ++t) {
            const short8 kf = ks[(t * 16 + m) * 8 + ((4 + Qd) ^ (m & 7))];
            #pragma unroll
            for (int mt = 0; mt < 2; ++mt)
                st[t][mt] = __builtin_amdgcn_mfma_f32_16x16x32_bf16(kf, qf[mt][1], st[t][mt], 0, 0, 0);
        }

        // ---- P = exp2(S^T) packed straight to bf16 B-frags ----
        union { short8 v; unsigned int u[4]; } pf[2][2];
        #pragma unroll
        for (int mt = 0; mt < 2; ++mt)
            #pragma unroll
            for (int s2 = 0; s2 < 2; ++s2)
                #pragma unroll
                for (int u = 0; u < 4; ++u) {
                    const int t = s2 * 2 + (u >> 1), r = (u & 1) * 2;
                    pf[mt][s2].u[u] = pk2(EXP2(st[t][mt][r]), EXP2(st[t][mt][r + 1]));
                }

        // ---- row-sum partials on the matrix pipe: sacc += 1 * P ----
        #pragma unroll
        for (int mt = 0; mt < 2; ++mt)
            #pragma unroll
            for (int s2 = 0; s2 < 2; ++s2)
                sacc[mt] = __builtin_amdgcn_mfma_f32_16x16x32_bf16(onesu.v, pf[mt][s2].v, sacc[mt], 0, 0, 0);

        // ---- O^T += V^T P ----
        #pragma unroll
        for (int s2 = 0; s2 < 2; ++s2)
            #pragma unroll
            for (int t2 = 0; t2 < 4; ++t2) {
                const short8 vf = vts[(t2 * 16 + m) * 8 + ((s2 * 4 + Qd) ^ (m & 7))];
                #pragma unroll
                for (int mt = 0; mt < 2; ++mt)
                    of[t2][mt] = __builtin_amdgcn_mfma_f32_16x16x32_bf16(vf, pf[mt][s2].v, of[t2][mt], 0, 0, 0);
            }
    }
    __syncthreads();   // all waves done reading LDS before reuse as scratch

    // ---- denominators: every lane of q-column m holds the full sum ----
    if (Qd == 0) {
        #pragma unroll
        for (int mt = 0; mt < 2; ++mt)
            sums[((size_t)part * NQROWS + row0 + w * 32 + mt * 16 + m) * NHEAD + h] = sacc[mt][0];
    }

    // ---- O^T -> O via LDS, coalesced bf16 b128 stores ----
    unsigned int* ob = (unsigned int*)smem;
    #pragma unroll
    for (int t2 = 0; t2 < 4; ++t2)
        #pragma unroll
        for (int mt = 0; mt < 2; ++mt) {
            const int qq  = w * 32 + mt * 16 + m;
            const int blk = t2 * 2 + (Qd >> 1);
            const int sub = (Qd & 1) * 2;
            const int bs  = (blk ^ (qq & 7)) * 4;
            ob[qq * 32 + bs + sub]     = pk2(of[t2][mt][0], of[t2][mt][1]);
            ob[qq * 32 + bs + sub + 1] = pk2(of[t2][mt][2], of[t2][mt][3]);
        }
    __syncthreads();
    #pragma unroll
    for (int pp = 0; pp < 4; ++pp) {
        const int idx = tid + pp * 256;
        const int qq = idx >> 3, sg = idx & 7;
        *(short8*)(AOp + (size_t)part * PART_ELEMS + (size_t)(row0 + qq) * DIM + h * HD + sg * 8) =
            smem[qq * 8 + (sg ^ (qq & 7))];
    }
}

// ---------------------------------------------------------------------------
// combine_kernel: AO = LN_512( (sum_p O_p)/(sum_p s_p) ), bf16,
// stored SEG-SWIZZLED for final's DMA staging.
// ---------------------------------------------------------------------------
__global__ __launch_bounds__(256) void combine_kernel(
    const unsigned short* __restrict__ AOp, const float* __restrict__ sums,
    const float* __restrict__ g, const float* __restrict__ be,
    unsigned short* __restrict__ AO)
{
    __shared__ float rs[256], rq[256], sm[2], sr[2];
    const int tid  = threadIdx.x;
    const int half = tid >> 7;
    const int row  = blockIdx.x * 2 + half;
    const int t    = tid & 127;                 // 4 cols per thread
    const int h    = t >> 4;

    float stot = 0.f;
    #pragma unroll
    for (int p = 0; p < 4; ++p)
        stot += sums[((size_t)p * NQROWS + row) * NHEAD + h];

    float o[4] = {0.f, 0.f, 0.f, 0.f};
    #pragma unroll
    for (int p = 0; p < 4; ++p) {
        const ushort4 u = *(const ushort4*)(AOp + (size_t)p * PART_ELEMS + (size_t)row * DIM + t * 4);
        o[0] += bf2f(u.x); o[1] += bf2f(u.y); o[2] += bf2f(u.z); o[3] += bf2f(u.w);
    }
    const float inv = 1.0f / stot;
    const float v0 = o[0] * inv, v1 = o[1] * inv, v2 = o[2] * inv, v3 = o[3] * inv;

    rs[tid] = v0 + v1 + v2 + v3;
    rq[tid] = v0 * v0 + v1 * v1 + v2 * v2 + v3 * v3;
    __syncthreads();
    #pragma unroll
    for (int off = 64; off > 0; off >>= 1) {
        if (t < off) { rs[tid] += rs[tid + off]; rq[tid] += rq[tid + off]; }
        __syncthreads();
    }
    if (t == 0) {
        const float mean = rs[tid] * (1.f / DIM);
        const float var  = rq[tid] * (1.f / DIM) - mean * mean;
        sm[half] = mean;
        sr[half] = rsqrtf(var + EPS);
    }
    __syncthreads();

    const float mean = sm[half], rstd = sr[half];
    const float4 g4 = *(const float4*)(g + t * 4);
    const float4 b4 = *(const float4*)(be + t * 4);
    uint2 packed;
    packed.x = pk2((v0 - mean) * rstd * g4.x + b4.x, (v1 - mean) * rstd * g4.y + b4.y);
    packed.y = pk2((v2 - mean) * rstd * g4.z + b4.z, (v3 - mean) * rstd * g4.w + b4.w);
    const int kt = t >> 4, seg = (t >> 1) & 7, jof = (t & 1) * 4;
    *(uint2*)(AO + (size_t)row * DIM + kt * 64 + ((seg ^ (row & 7)) << 3) + jof) = packed;
}

// ---------------------------------------------------------------------------
// final_kernel: pure bf16 GEMM out = AO @ Wproj^T.  3-buffer depth-2
// DMA pipeline with counted vmcnt + raw s_barrier.
// ---------------------------------------------------------------------------
__global__ __launch_bounds__(256) void final_kernel(
    const unsigned short* __restrict__ AO, const unsigned short* __restrict__ Wpb,
    float* __restrict__ out)
{
    __shared__ short8 fs[3072];            // 48 KB: buf p = fs + p*1024 (A 512 | B 512)
    const int tid  = threadIdx.x;
    const int w    = tid >> 6, lane = tid & 63, m = lane & 15, q = lane >> 4;
    const int row0 = blockIdx.x * 64;
    const int col0 = blockIdx.y * 64;

    const int it0 = tid, it1 = tid + 256;
    const unsigned short* asrc0 = AO  + (size_t)(row0 + (it0 >> 3)) * DIM + (it0 & 7) * 8;
    const unsigned short* asrc1 = AO  + (size_t)(row0 + (it1 >> 3)) * DIM + (it1 & 7) * 8;
    const unsigned short* wsrc0 = Wpb + (size_t)(col0 + (it0 >> 3)) * DIM + (it0 & 7) * 8;
    const unsigned short* wsrc1 = Wpb + (size_t)(col0 + (it1 >> 3)) * DIM + (it1 & 7) * 8;

    floatx4 acc[4];
    #pragma unroll
    for (int mt = 0; mt < 4; ++mt) acc[mt] = (floatx4){0.f, 0.f, 0.f, 0.f};

    {   // DMA tiles 0 -> buf0, 1 -> buf1
        dma16(asrc0, fs + w * 64);
        dma16(asrc1, fs + 256 + w * 64);
        dma16(wsrc0, fs + 512 + w * 64);
        dma16(wsrc1, fs + 768 + w * 64);
        dma16(asrc0 + 64, fs + 1024 + w * 64);
        dma16(asrc1 + 64, fs + 1024 + 256 + w * 64);
        dma16(wsrc0 + 64, fs + 1024 + 512 + w * 64);
        dma16(wsrc1 + 64, fs + 1024 + 768 + w * 64);
    }

    int cb = 0, nb = 2;
    for (int kt = 0; kt < 8; ++kt) {
        if (kt < 7) asm volatile("s_waitcnt vmcnt(4)" ::: "memory");
        else        asm volatile("s_waitcnt vmcnt(0)" ::: "memory");
        __builtin_amdgcn_s_barrier();
        __builtin_amdgcn_sched_barrier(0);

        short8* buf = fs + cb * 1024;
        if (kt < 6) {
            short8* bufn = fs + nb * 1024;
            const int o = (kt + 2) * 64;
            dma16(asrc0 + o, bufn + w * 64);
            dma16(asrc1 + o, bufn + 256 + w * 64);
            dma16(wsrc0 + o, bufn + 512 + w * 64);
            dma16(wsrc1 + o, bufn + 768 + w * 64);
        }
        #pragma unroll
        for (int s = 0; s < 2; ++s) {
            short8 af[4];
            #pragma unroll
            for (int mt = 0; mt < 4; ++mt)
                af[mt] = buf[(mt * 16 + m) * 8 + ((s * 4 + q) ^ (m & 7))];
            const short8 bfr = buf[512 + (w * 16 + m) * 8 + ((s * 4 + q) ^ (m & 7))];
            #pragma unroll
            for (int mt = 0; mt < 4; ++mt)
                acc[mt] = __builtin_amdgcn_mfma_f32_16x16x32_bf16(af[mt], bfr, acc[mt], 0, 0, 0);
        }
        cb = (cb == 2) ? 0 : cb + 1;
        nb = (nb == 2) ? 0 : nb + 1;
    }

    #pragma unroll
    for (int mt = 0; mt < 4; ++mt)
        #pragma unroll
        for (int r = 0; r < 4; ++r)
            out[(size_t)(row0 + mt * 16 + q * 4 + r) * DIM + col0 + w * 16 + m] = acc[mt][r];
}

// ---------------------------------------------------------------------------
extern "C" void kernel_launch(void* const* d_in, const int* in_sizes, int n_in,
                              void* d_out, int out_size, void* d_ws, size_t ws_size,
                              hipStream_t stream)
{
    const float* x_q = (const float*)d_in[0];
    const float* x_k = (const float*)d_in[1];
    const float* x_v = (const float*)d_in[2];
    const float* Wq  = (const float*)d_in[3];
    const float* Wk  = (const float*)d_in[4];
    const float* Wv  = (const float*)d_in[5];
    const float* Wp  = (const float*)d_in[6];
    const float* qg  = (const float*)d_in[7];
    const float* qb  = (const float*)d_in[8];
    const float* kg  = (const float*)d_in[9];
    const float* kb  = (const float*)d_in[10];
    const float* ng  = (const float*)d_in[11];
    const float* nb  = (const float*)d_in[12];
    float* out = (float*)d_out;

    // ws: Qb|Kb|VTb (bf16, 4 MB each) | AOp (4x4 MB) | sums 512 KB | Wb 2 MB.
    // Xb (bf16 x, 12 MB) aliases AOp: dead before attn_kernel writes AOp.
    unsigned short* Qb   = (unsigned short*)d_ws;
    unsigned short* Kb   = Qb  + (size_t)NQROWS * DIM;
    unsigned short* VTb  = Kb  + (size_t)NBANK * DIM;
    unsigned short* AOp  = VTb + (size_t)NBANK * DIM;
    float*          sums = (float*)(AOp + (size_t)4 * PART_ELEMS);
    unsigned short* Wb   = (unsigned short*)(sums + (size_t)4 * NQROWS * NHEAD);
    unsigned short* Xb   = AOp;  // alias: Xb consumed by qkv before attn writes AOp
    unsigned short* AO   = Qb;   // alias: Qb dead after attn_kernel

    cvt_kernel<<<dim3(1024, 7), 256, 0, stream>>>(Wq, Wk, Wv, Wp, x_q, x_k, x_v, Wb, Xb);
    qkv_kernel<<<dim3(64, 12), 256, 0, stream>>>(Xb, Wb, qg, qb, kg, kb, Qb, Kb, VTb);
    attn_kernel<<<dim3(256, 4), 256, 0, stream>>>(Qb, Kb, VTb, AOp, sums);
    combine_kernel<<<NQROWS / 2, 256, 0, stream>>>(AOp, sums, ng, nb, AO);
    final_kernel<<<dim3(64, 8), 256, 0, stream>>>(AO, Wb + (size_t)3 * DIM * DIM, out);
}

// Round 7
// 155.377 us; speedup vs baseline: 1.0451x; 1.0451x over previous
//
#include <hip/hip_runtime.h>
#include <hip/hip_bf16.h>
#include <math.h>

#define DIM 512
#define NHEAD 8
#define HD 64
#define NBANK 4096
#define NQROWS 4096
#define EPS 1e-5f
// 0.125 * log2(e): exp() folded into exp2() domain at the Q epilogue
#define QSCALE 0.18033688011f
#define PART_ELEMS (NQROWS * DIM)   // one O-partial buffer (bf16 elems)

typedef __attribute__((ext_vector_type(4))) float floatx4;
typedef __attribute__((ext_vector_type(8))) short short8;

#if defined(__has_builtin)
#if __has_builtin(__builtin_amdgcn_exp2f)
#define EXP2(x) __builtin_amdgcn_exp2f(x)
#endif
#endif
#ifndef EXP2
#define EXP2(x) exp2f(x)
#endif

__device__ __forceinline__ unsigned short f2bf(float f) {
    unsigned int u = __float_as_uint(f);
    u += 0x7fffu + ((u >> 16) & 1u);          // round-to-nearest-even
    return (unsigned short)(u >> 16);
}
__device__ __forceinline__ float bf2f(unsigned short h) {
    return __uint_as_float(((unsigned int)h) << 16);
}
// packed fp32x2 -> bf16x2 (v_cvt_pk_bf16_f32), low short = a
__device__ __forceinline__ unsigned int pk2(float a, float b) {
    union { __hip_bfloat162 h; unsigned int u; } cvt;
    cvt.h = __float22bfloat162_rn(make_float2(a, b));
    return cvt.u;
}
// async 16B global -> LDS DMA (global_load_lds_dwordx4).  gsrc per-lane,
// ldst wave-uniform slab base; HW adds lane*16.
__device__ __forceinline__ void dma16(const void* gsrc, void* ldst) {
    __builtin_amdgcn_global_load_lds(
        (const __attribute__((address_space(1))) unsigned int*)gsrc,
        (__attribute__((address_space(3))) unsigned int*)ldst, 16, 0, 0);
}

// ---------------------------------------------------------------------------
// cvt_kernel R16: fp32 -> bf16, SEG-SWIZZLED per 64-elem k-tile:
// dst[row][kt][seg^(row&7)] = src[row][kt*64+seg*8 ..8] -> consumers DMA linearly.
// FLAT grid (3584 blocks, no dead blocks): bid<512 -> W mats (y=bid>>7),
// else X mats (y=4+(bid-512)>>10).
// ---------------------------------------------------------------------------
__global__ __launch_bounds__(256) void cvt_kernel(
    const float* __restrict__ Wq, const float* __restrict__ Wk,
    const float* __restrict__ Wv, const float* __restrict__ Wp,
    const float* __restrict__ xq, const float* __restrict__ xk,
    const float* __restrict__ xv,
    unsigned short* __restrict__ Wb, unsigned short* __restrict__ Xb)
{
    const int bid = blockIdx.x;
    int y, bx;
    if (bid < 512) { y = bid >> 7; bx = bid & 127; }
    else { const int t2 = bid - 512; y = 4 + (t2 >> 10); bx = t2 & 1023; }
    const float* src;
    unsigned short* dst;
    if (y < 4) {
        src = (y == 0) ? Wq : (y == 1) ? Wk : (y == 2) ? Wv : Wp;
        dst = Wb + (size_t)y * DIM * DIM;
    } else {
        src = (y == 4) ? xq : (y == 5) ? xk : xv;
        dst = Xb + (size_t)(y - 4) * NQROWS * DIM;
    }
    const int i = (bx * 256 + threadIdx.x) * 8;
    const int row = i >> 9, kpos = i & 511;
    const int kt = kpos >> 6, seg = (kpos >> 3) & 7;
    const float4 a0 = *(const float4*)(src + i);
    const float4 a1 = *(const float4*)(src + i + 4);
    union { short8 v; unsigned int u[4]; } t;
    t.u[0] = pk2(a0.x, a0.y); t.u[1] = pk2(a0.z, a0.w);
    t.u[2] = pk2(a1.x, a1.y); t.u[3] = pk2(a1.z, a1.w);
    *(short8*)(dst + (size_t)row * 512 + kt * 64 + ((seg ^ (row & 7)) << 3)) = t.v;
}

// ---------------------------------------------------------------------------
// qkv_kernel: 64x128 tiles, ping-pong, one barrier/k-iter.  BOTH operands
// (pre-swizzled bf16 Xb / Wb) staged via global_load_lds DMA.
// Epilogues write ATTN-READY layouts.
// ---------------------------------------------------------------------------
__global__ __launch_bounds__(256) void qkv_kernel(
    const unsigned short* __restrict__ Xb, const unsigned short* __restrict__ Wb,
    const float* __restrict__ qg, const float* __restrict__ qbeta,
    const float* __restrict__ kg, const float* __restrict__ kbeta,
    unsigned short* __restrict__ Qb, unsigned short* __restrict__ Kb,
    unsigned short* __restrict__ VTb)
{
    __shared__ short8 smem[3072];   // 48 KB: buf p = smem + p*1536 (A 512 | B 1024)
    const int tid  = threadIdx.x;
    const int w    = tid >> 6, lane = tid & 63, m = lane & 15, q = lane >> 4;
    const int wr   = w & 1, wc = w >> 1;
    const int row0 = blockIdx.x * 64;
    const int mat  = blockIdx.y >> 2;
    const int col0 = (blockIdx.y & 3) * 128;
    const unsigned short* Xm = Xb + (size_t)mat * NQROWS * DIM;
    const unsigned short* Wm = Wb + (size_t)mat * DIM * DIM;

    // DMA sources: per-lane global addr, wave-uniform LDS dest slab.
    const int it0 = tid, it1 = tid + 256;
    const unsigned short* asrc0 = Xm + (size_t)(row0 + (it0 >> 3)) * DIM + (it0 & 7) * 8;
    const unsigned short* asrc1 = Xm + (size_t)(row0 + (it1 >> 3)) * DIM + (it1 & 7) * 8;
    const unsigned short* bsrc[4];
    #pragma unroll
    for (int j = 0; j < 4; ++j) {
        const int item = j * 256 + tid;
        bsrc[j] = Wm + (size_t)(col0 + (item >> 3)) * DIM + (item & 7) * 8;
    }

    floatx4 acc[2][4];
    #pragma unroll
    for (int mt = 0; mt < 2; ++mt)
        #pragma unroll
        for (int nt = 0; nt < 4; ++nt) acc[mt][nt] = (floatx4){0.f, 0.f, 0.f, 0.f};

    {   // DMA tile 0 -> buf0
        short8* as = smem; short8* bs = smem + 512;
        dma16(asrc0, as + w * 64);
        dma16(asrc1, as + 256 + w * 64);
        #pragma unroll
        for (int j = 0; j < 4; ++j)
            dma16(bsrc[j], bs + j * 256 + w * 64);
    }
    __syncthreads();

    for (int kt = 0; kt < 8; ++kt) {
        short8* as = smem + (kt & 1) * 1536;
        short8* bs = as + 512;
        if (kt < 7) {              // DMA tile kt+1 -> other buf (overlaps compute)
            short8* asn = smem + ((kt + 1) & 1) * 1536;
            short8* bsn = asn + 512;
            const int o = (kt + 1) * 64;
            dma16(asrc0 + o, asn + w * 64);
            dma16(asrc1 + o, asn + 256 + w * 64);
            #pragma unroll
            for (int j = 0; j < 4; ++j)
                dma16(bsrc[j] + o, bsn + j * 256 + w * 64);
        }
        #pragma unroll
        for (int s = 0; s < 2; ++s) {
            short8 af[2], bfr[4];
            #pragma unroll
            for (int mt = 0; mt < 2; ++mt)
                af[mt] = as[(wr * 32 + mt * 16 + m) * 8 + ((s * 4 + q) ^ (m & 7))];
            #pragma unroll
            for (int nt = 0; nt < 4; ++nt)
                bfr[nt] = bs[(wc * 64 + nt * 16 + m) * 8 + ((s * 4 + q) ^ (m & 7))];
            #pragma unroll
            for (int mt = 0; mt < 2; ++mt)
                #pragma unroll
                for (int nt = 0; nt < 4; ++nt)
                    acc[mt][nt] = __builtin_amdgcn_mfma_f32_16x16x32_bf16(af[mt], bfr[nt], acc[mt][nt], 0, 0, 0);
        }
        __syncthreads();
    }

    if (mat < 2) {
        const float* g = (mat == 0) ? qg : kg;
        const float* be = (mat == 0) ? qbeta : kbeta;
        unsigned short* Y = (mat == 0) ? Qb : Kb;
        float gv[4], bv[4];
        #pragma unroll
        for (int nt = 0; nt < 4; ++nt) { gv[nt] = g[nt * 16 + m]; bv[nt] = be[nt * 16 + m]; }
        #pragma unroll
        for (int mt = 0; mt < 2; ++mt) {
            #pragma unroll
            for (int r = 0; r < 4; ++r) {
                float s = 0.f, sq = 0.f;
                #pragma unroll
                for (int nt = 0; nt < 4; ++nt) { const float v = acc[mt][nt][r]; s += v; sq += v * v; }
                s  += __shfl_xor(s, 1);  s  += __shfl_xor(s, 2);  s  += __shfl_xor(s, 4);  s  += __shfl_xor(s, 8);
                sq += __shfl_xor(sq, 1); sq += __shfl_xor(sq, 2); sq += __shfl_xor(sq, 4); sq += __shfl_xor(sq, 8);
                const float mean = s * (1.f / HD);
                const float var  = sq * (1.f / HD) - mean * mean;
                const float rr   = rsqrtf(var + EPS);
                const int grow = row0 + wr * 32 + mt * 16 + q * 4 + r;
                #pragma unroll
                for (int nt = 0; nt < 4; ++nt) {
                    float v = (acc[mt][nt][r] - mean) * rr * gv[nt] + bv[nt];
                    if (mat == 0) v *= QSCALE;
                    const int col = col0 + wc * 64 + nt * 16 + m;
                    int scol = col;
                    if (mat == 1) {   // K: seg-swizzle within head slice by n
                        const int o = col & 63, sg2 = o >> 3;
                        scol = (col & ~63) | (((sg2 ^ (grow & 7)) << 3) | (o & 7));
                    }
                    Y[(size_t)grow * DIM + scol] = f2bf(v);
                }
            }
        }
    } else {
        // V: transpose via LDS (stride 88), then pack VTb[h][chunk][item]
        // item(d,g) = dl*8 + (g^(dl&7)); value = rows {pos..pos+3, pos+16..+19}
        unsigned short* vt = (unsigned short*)smem;
        __syncthreads();
        #pragma unroll
        for (int mt = 0; mt < 2; ++mt)
            #pragma unroll
            for (int nt = 0; nt < 4; ++nt) {
                const int c  = wc * 64 + nt * 16 + m;
                const int rw = wr * 32 + mt * 16 + q * 4;
                *(unsigned int*)(vt + c * 88 + rw)     = pk2(acc[mt][nt][0], acc[mt][nt][1]);
                *(unsigned int*)(vt + c * 88 + rw + 2) = pk2(acc[mt][nt][2], acc[mt][nt][3]);
            }
        __syncthreads();
        #pragma unroll
        for (int p = 0; p < 4; ++p) {
            const int idx = p * 256 + tid;       // 1024 = 128 c x 8 g
            const int c = idx >> 3, g = idx & 7;
            const int dglob = col0 + c, hh = dglob >> 6, dl = dglob & 63;
            const int pos = (g >> 2) * 32 + (g & 3) * 4;
            union { short8 v; ushort4 h4[2]; } tv;
            tv.h4[0] = *(const ushort4*)(vt + c * 88 + pos);
            tv.h4[1] = *(const ushort4*)(vt + c * 88 + pos + 16);
            *(short8*)(VTb + ((size_t)(hh * 64 + blockIdx.x) * 512
                              + dl * 8 + (g ^ (dl & 7))) * 8) = tv.v;
        }
    }
}

// ---------------------------------------------------------------------------
// attn_kernel R15: R13 structure (K triple / V double buffered, 40 KB LDS =
// 4 blocks/CU, counted vmcnt(2), unrolled) + row-sums on the matrix pipe:
// sacc += ones * P (4 MFMA per chunk replaces 32 v_add + 2 shuffles).
// ---------------------------------------------------------------------------
__global__ __launch_bounds__(256, 4) void attn_kernel(
    const unsigned short* __restrict__ Qb, const unsigned short* __restrict__ Kb,
    const unsigned short* __restrict__ VTb, unsigned short* __restrict__ AOp,
    float* __restrict__ sums)
{
    // 40 KB: kbuf p = smem + p*512 (p=0..2), vbuf p = smem + 1536 + p*512 (p=0..1)
    __shared__ short8 smem[2560];
    const int tid  = threadIdx.x;
    const int w    = tid >> 6;
    const int lane = tid & 63;
    const int m    = lane & 15;
    const int Qd   = lane >> 4;
    const int h    = blockIdx.x & 7;
    const int qgi  = blockIdx.x >> 3;        // 0..31
    const int row0 = qgi * 128;
    const int part = blockIdx.y;
    const int c0   = part * 16;              // first chunk index

    // per-lane DMA sources (chunk-relative), 2 items each for K and V
    const int it0 = tid, it1 = tid + 256;    // item indices
    const unsigned short* ksrc0 = Kb + (size_t)(it0 >> 3) * DIM + h * HD + (it0 & 7) * 8;
    const unsigned short* ksrc1 = Kb + (size_t)(it1 >> 3) * DIM + h * HD + (it1 & 7) * 8;
    const unsigned short* vbase = VTb + (size_t)h * 64 * 512 * 8;

    short8 qf[2][2];
    #pragma unroll
    for (int mt = 0; mt < 2; ++mt)
        #pragma unroll
        for (int s = 0; s < 2; ++s)
            qf[mt][s] = *(const short8*)(Qb + (size_t)(row0 + w * 32 + mt * 16 + m) * DIM
                                         + h * HD + s * 32 + Qd * 8);

    floatx4 of[4][2];
    floatx4 sacc[2];
    #pragma unroll
    for (int t = 0; t < 4; ++t)
        #pragma unroll
        for (int mt = 0; mt < 2; ++mt) of[t][mt] = (floatx4){0.f, 0.f, 0.f, 0.f};
    #pragma unroll
    for (int mt = 0; mt < 2; ++mt) sacc[mt] = (floatx4){0.f, 0.f, 0.f, 0.f};
    const floatx4 fz = (floatx4){0.f, 0.f, 0.f, 0.f};
    union { short8 v; unsigned int u[4]; } onesu;
    #pragma unroll
    for (int u = 0; u < 4; ++u) onesu.u[u] = 0x3F803F80u;   // bf16 1.0 x2

    // prologue (issue order matters for vmcnt counts): K[0], V[0], K[1]
    {
        dma16(ksrc0 + (size_t)c0 * 64 * DIM, smem + w * 64);
        dma16(ksrc1 + (size_t)c0 * 64 * DIM, smem + 256 + w * 64);
        dma16(vbase + ((size_t)c0 * 512 + it0) * 8, smem + 1536 + w * 64);
        dma16(vbase + ((size_t)c0 * 512 + it1) * 8, smem + 1536 + 256 + w * 64);
        dma16(ksrc0 + ((size_t)c0 + 1) * 64 * DIM, smem + 512 + w * 64);
        dma16(ksrc1 + ((size_t)c0 + 1) * 64 * DIM, smem + 512 + 256 + w * 64);
    }

    #pragma unroll
    for (int c = 0; c < 16; ++c) {
        // queue (oldest->newest): K[c](2), V[c](2), K[c+1](2).
        // Need K[c],V[c] -> leave K[c+1]'s 2 in flight.
        if (c < 15) asm volatile("s_waitcnt vmcnt(2)" ::: "memory");
        else        asm volatile("s_waitcnt vmcnt(0)" ::: "memory");
        __builtin_amdgcn_s_barrier();
        __builtin_amdgcn_sched_barrier(0);

        short8* ks  = smem + (c % 3) * 512;
        short8* vts = smem + 1536 + (c & 1) * 512;
        if (c < 15) {            // V[c+1] -> buffer of V[c-1] (read done at barrier)
            short8* vtsn = smem + 1536 + ((c + 1) & 1) * 512;
            const size_t nc = (size_t)(c0 + c + 1);
            dma16(vbase + (nc * 512 + it0) * 8, vtsn + w * 64);
            dma16(vbase + (nc * 512 + it1) * 8, vtsn + 256 + w * 64);
        }
        if (c < 14) {            // K[c+2] -> buffer of K[c-1] (read done at barrier)
            short8* ksn = smem + ((c + 2) % 3) * 512;
            const size_t nc2 = (size_t)(c0 + c + 2);
            dma16(ksrc0 + nc2 * 64 * DIM, ksn + w * 64);
            dma16(ksrc1 + nc2 * 64 * DIM, ksn + 256 + w * 64);
        }

        // ---- S^T = K Q^T (zero-C first MFMA: no st zero-init movs) ----
        floatx4 st[4][2];
        #pragma unroll
        for (int t = 0; t < 4; ++t) {
            const short8 kf = ks[(t * 16 + m) * 8 + (Qd ^ (m & 7))];
            #pragma unroll
            for (int mt = 0; mt < 2; ++mt)
                st[t][mt] = __builtin_amdgcn_mfma_f32_16x16x32_bf16(kf, qf[mt][0], fz, 0, 0, 0);
        }
        #pragma unroll
        for (int t = 0; t < 4; ++t) {
            const short8 kf = ks[(t * 16 + m) * 8 + ((4 + Qd) ^ (m & 7))];
            #pragma unroll
            for (int mt = 0; mt < 2; ++mt)
                st[t][mt] = __builtin_amdgcn_mfma_f32_16x16x32_bf16(kf, qf[mt][1], st[t][mt], 0, 0, 0);
        }

        // ---- P = exp2(S^T) packed straight to bf16 B-frags ----
        union { short8 v; unsigned int u[4]; } pf[2][2];
        #pragma unroll
        for (int mt = 0; mt < 2; ++mt)
            #pragma unroll
            for (int s2 = 0; s2 < 2; ++s2)
                #pragma unroll
                for (int u = 0; u < 4; ++u) {
                    const int t = s2 * 2 + (u >> 1), r = (u & 1) * 2;
                    pf[mt][s2].u[u] = pk2(EXP2(st[t][mt][r]), EXP2(st[t][mt][r + 1]));
                }

        // ---- row-sum partials on the matrix pipe: sacc += 1 * P ----
        #pragma unroll
        for (int mt = 0; mt < 2; ++mt)
            #pragma unroll
            for (int s2 = 0; s2 < 2; ++s2)
                sacc[mt] = __builtin_amdgcn_mfma_f32_16x16x32_bf16(onesu.v, pf[mt][s2].v, sacc[mt], 0, 0, 0);

        // ---- O^T += V^T P ----
        #pragma unroll
        for (int s2 = 0; s2 < 2; ++s2)
            #pragma unroll
            for (int t2 = 0; t2 < 4; ++t2) {
                const short8 vf = vts[(t2 * 16 + m) * 8 + ((s2 * 4 + Qd) ^ (m & 7))];
                #pragma unroll
                for (int mt = 0; mt < 2; ++mt)
                    of[t2][mt] = __builtin_amdgcn_mfma_f32_16x16x32_bf16(vf, pf[mt][s2].v, of[t2][mt], 0, 0, 0);
            }
    }
    __syncthreads();   // all waves done reading LDS before reuse as scratch

    // ---- denominators: every lane of q-column m holds the full sum ----
    if (Qd == 0) {
        #pragma unroll
        for (int mt = 0; mt < 2; ++mt)
            sums[((size_t)part * NQROWS + row0 + w * 32 + mt * 16 + m) * NHEAD + h] = sacc[mt][0];
    }

    // ---- O^T -> O via LDS, coalesced bf16 b128 stores ----
    unsigned int* ob = (unsigned int*)smem;
    #pragma unroll
    for (int t2 = 0; t2 < 4; ++t2)
        #pragma unroll
        for (int mt = 0; mt < 2; ++mt) {
            const int qq  = w * 32 + mt * 16 + m;
            const int blk = t2 * 2 + (Qd >> 1);
            const int sub = (Qd & 1) * 2;
            const int bs  = (blk ^ (qq & 7)) * 4;
            ob[qq * 32 + bs + sub]     = pk2(of[t2][mt][0], of[t2][mt][1]);
            ob[qq * 32 + bs + sub + 1] = pk2(of[t2][mt][2], of[t2][mt][3]);
        }
    __syncthreads();
    #pragma unroll
    for (int pp = 0; pp < 4; ++pp) {
        const int idx = tid + pp * 256;
        const int qq = idx >> 3, sg = idx & 7;
        *(short8*)(AOp + (size_t)part * PART_ELEMS + (size_t)(row0 + qq) * DIM + h * HD + sg * 8) =
            smem[qq * 8 + (sg ^ (qq & 7))];
    }
}

// ---------------------------------------------------------------------------
// combine_kernel R16: one ROW per WAVE (4 rows / 256-thr block, 1024 blocks).
// Zero barriers, zero LDS: lane l owns cols l*8..l*8+7 (one short8 segment),
// row stats via 6-step __shfl_xor over the 64-lane wave.  Output stays
// SEG-SWIZZLED for final's DMA staging (lane's 8 cols = exactly one segment).
// ---------------------------------------------------------------------------
__global__ __launch_bounds__(256) void combine_kernel(
    const unsigned short* __restrict__ AOp, const float* __restrict__ sums,
    const float* __restrict__ g, const float* __restrict__ be,
    unsigned short* __restrict__ AO)
{
    const int tid  = threadIdx.x;
    const int w    = tid >> 6;
    const int lane = tid & 63;
    const int row  = blockIdx.x * 4 + w;
    const int h    = lane >> 3;                 // head of this lane's 8 cols

    float stot = 0.f;
    #pragma unroll
    for (int p = 0; p < 4; ++p)
        stot += sums[((size_t)p * NQROWS + row) * NHEAD + h];

    float o[8] = {0.f, 0.f, 0.f, 0.f, 0.f, 0.f, 0.f, 0.f};
    #pragma unroll
    for (int p = 0; p < 4; ++p) {
        const short8 u = *(const short8*)(AOp + (size_t)p * PART_ELEMS + (size_t)row * DIM + lane * 8);
        #pragma unroll
        for (int j = 0; j < 8; ++j)
            o[j] += bf2f((unsigned short)u[j]);
    }
    const float inv = 1.0f / stot;
    float v[8];
    float s = 0.f, sq = 0.f;
    #pragma unroll
    for (int j = 0; j < 8; ++j) {
        v[j] = o[j] * inv;
        s  += v[j];
        sq += v[j] * v[j];
    }
    #pragma unroll
    for (int off = 1; off < 64; off <<= 1) {
        s  += __shfl_xor(s, off);
        sq += __shfl_xor(sq, off);
    }
    const float mean = s * (1.f / DIM);
    const float var  = sq * (1.f / DIM) - mean * mean;
    const float rstd = rsqrtf(var + EPS);

    const float4 g0 = *(const float4*)(g + lane * 8);
    const float4 g1 = *(const float4*)(g + lane * 8 + 4);
    const float4 b0 = *(const float4*)(be + lane * 8);
    const float4 b1 = *(const float4*)(be + lane * 8 + 4);
    union { short8 v; unsigned int u[4]; } pk;
    pk.u[0] = pk2((v[0] - mean) * rstd * g0.x + b0.x, (v[1] - mean) * rstd * g0.y + b0.y);
    pk.u[1] = pk2((v[2] - mean) * rstd * g0.z + b0.z, (v[3] - mean) * rstd * g0.w + b0.w);
    pk.u[2] = pk2((v[4] - mean) * rstd * g1.x + b1.x, (v[5] - mean) * rstd * g1.y + b1.y);
    pk.u[3] = pk2((v[6] - mean) * rstd * g1.z + b1.z, (v[7] - mean) * rstd * g1.w + b1.w);
    const int kt = lane >> 3, seg = lane & 7;
    *(short8*)(AO + (size_t)row * DIM + kt * 64 + ((seg ^ (row & 7)) << 3)) = pk.v;
}

// ---------------------------------------------------------------------------
// final_kernel: pure bf16 GEMM out = AO @ Wproj^T.  3-buffer depth-2
// DMA pipeline with counted vmcnt + raw s_barrier.
// ---------------------------------------------------------------------------
__global__ __launch_bounds__(256) void final_kernel(
    const unsigned short* __restrict__ AO, const unsigned short* __restrict__ Wpb,
    float* __restrict__ out)
{
    __shared__ short8 fs[3072];            // 48 KB: buf p = fs + p*1024 (A 512 | B 512)
    const int tid  = threadIdx.x;
    const int w    = tid >> 6, lane = tid & 63, m = lane & 15, q = lane >> 4;
    const int row0 = blockIdx.x * 64;
    const int col0 = blockIdx.y * 64;

    const int it0 = tid, it1 = tid + 256;
    const unsigned short* asrc0 = AO  + (size_t)(row0 + (it0 >> 3)) * DIM + (it0 & 7) * 8;
    const unsigned short* asrc1 = AO  + (size_t)(row0 + (it1 >> 3)) * DIM + (it1 & 7) * 8;
    const unsigned short* wsrc0 = Wpb + (size_t)(col0 + (it0 >> 3)) * DIM + (it0 & 7) * 8;
    const unsigned short* wsrc1 = Wpb + (size_t)(col0 + (it1 >> 3)) * DIM + (it1 & 7) * 8;

    floatx4 acc[4];
    #pragma unroll
    for (int mt = 0; mt < 4; ++mt) acc[mt] = (floatx4){0.f, 0.f, 0.f, 0.f};

    {   // DMA tiles 0 -> buf0, 1 -> buf1
        dma16(asrc0, fs + w * 64);
        dma16(asrc1, fs + 256 + w * 64);
        dma16(wsrc0, fs + 512 + w * 64);
        dma16(wsrc1, fs + 768 + w * 64);
        dma16(asrc0 + 64, fs + 1024 + w * 64);
        dma16(asrc1 + 64, fs + 1024 + 256 + w * 64);
        dma16(wsrc0 + 64, fs + 1024 + 512 + w * 64);
        dma16(wsrc1 + 64, fs + 1024 + 768 + w * 64);
    }

    int cb = 0, nb = 2;
    for (int kt = 0; kt < 8; ++kt) {
        if (kt < 7) asm volatile("s_waitcnt vmcnt(4)" ::: "memory");
        else        asm volatile("s_waitcnt vmcnt(0)" ::: "memory");
        __builtin_amdgcn_s_barrier();
        __builtin_amdgcn_sched_barrier(0);

        short8* buf = fs + cb * 1024;
        if (kt < 6) {
            short8* bufn = fs + nb * 1024;
            const int o = (kt + 2) * 64;
            dma16(asrc0 + o, bufn + w * 64);
            dma16(asrc1 + o, bufn + 256 + w * 64);
            dma16(wsrc0 + o, bufn + 512 + w * 64);
            dma16(wsrc1 + o, bufn + 768 + w * 64);
        }
        #pragma unroll
        for (int s = 0; s < 2; ++s) {
            short8 af[4];
            #pragma unroll
            for (int mt = 0; mt < 4; ++mt)
                af[mt] = buf[(mt * 16 + m) * 8 + ((s * 4 + q) ^ (m & 7))];
            const short8 bfr = buf[512 + (w * 16 + m) * 8 + ((s * 4 + q) ^ (m & 7))];
            #pragma unroll
            for (int mt = 0; mt < 4; ++mt)
                acc[mt] = __builtin_amdgcn_mfma_f32_16x16x32_bf16(af[mt], bfr, acc[mt], 0, 0, 0);
        }
        cb = (cb == 2) ? 0 : cb + 1;
        nb = (nb == 2) ? 0 : nb + 1;
    }

    #pragma unroll
    for (int mt = 0; mt < 4; ++mt)
        #pragma unroll
        for (int r = 0; r < 4; ++r)
            out[(size_t)(row0 + mt * 16 + q * 4 + r) * DIM + col0 + w * 16 + m] = acc[mt][r];
}

// ---------------------------------------------------------------------------
extern "C" void kernel_launch(void* const* d_in, const int* in_sizes, int n_in,
                              void* d_out, int out_size, void* d_ws, size_t ws_size,
                              hipStream_t stream)
{
    const float* x_q = (const float*)d_in[0];
    const float* x_k = (const float*)d_in[1];
    const float* x_v = (const float*)d_in[2];
    const float* Wq  = (const float*)d_in[3];
    const float* Wk  = (const float*)d_in[4];
    const float* Wv  = (const float*)d_in[5];
    const float* Wp  = (const float*)d_in[6];
    const float* qg  = (const float*)d_in[7];
    const float* qb  = (const float*)d_in[8];
    const float* kg  = (const float*)d_in[9];
    const float* kb  = (const float*)d_in[10];
    const float* ng  = (const float*)d_in[11];
    const float* nb  = (const float*)d_in[12];
    float* out = (float*)d_out;

    // ws: Qb|Kb|VTb (bf16, 4 MB each) | AOp (4x4 MB) | sums 512 KB | Wb 2 MB.
    // Xb (bf16 x, 12 MB) aliases AOp: dead before attn_kernel writes AOp.
    unsigned short* Qb   = (unsigned short*)d_ws;
    unsigned short* Kb   = Qb  + (size_t)NQROWS * DIM;
    unsigned short* VTb  = Kb  + (size_t)NBANK * DIM;
    unsigned short* AOp  = VTb + (size_t)NBANK * DIM;
    float*          sums = (float*)(AOp + (size_t)4 * PART_ELEMS);
    unsigned short* Wb   = (unsigned short*)(sums + (size_t)4 * NQROWS * NHEAD);
    unsigned short* Xb   = AOp;  // alias: Xb consumed by qkv before attn writes AOp
    unsigned short* AO   = Qb;   // alias: Qb dead after attn_kernel

    cvt_kernel<<<3584, 256, 0, stream>>>(Wq, Wk, Wv, Wp, x_q, x_k, x_v, Wb, Xb);
    qkv_kernel<<<dim3(64, 12), 256, 0, stream>>>(Xb, Wb, qg, qb, kg, kb, Qb, Kb, VTb);
    attn_kernel<<<dim3(256, 4), 256, 0, stream>>>(Qb, Kb, VTb, AOp, sums);
    combine_kernel<<<NQROWS / 4, 256, 0, stream>>>(AOp, sums, ng, nb, AO);
    final_kernel<<<dim3(64, 8), 256, 0, stream>>>(AO, Wb + (size_t)3 * DIM * DIM, out);
}